// Round 4
// baseline (287.893 us; speedup 1.0000x reference)
//
#include <hip/hip_runtime.h>
#include <math.h>

#define TLEN 512
#define NCH  128
#define KP   4
#define PMAXV 64
#define CMAXV 32
#define MINP 16
#define NSEQ 4096   // B*N = 32*128
#define OUTG ((size_t)NSEQ * KP * CMAXV * PMAXV)   // 33,554,432

// LDS bank-conflict padding: insert one element every 16
#define PAD(i) ((i) + ((i) >> 4))

// native vector type for nontemporal builtin (HIP float4 is a struct)
typedef float nfloat4 __attribute__((ext_vector_type(4)));

// ---- tiny setup kernel: twiddle table W[j] = exp(-2*pi*i*j/512) into ws ----
__global__ void twiddle_setup(double2* __restrict__ Wg) {
    const int j = threadIdx.x;    // 256 threads
    double ang = -6.283185307179586476925286766559 * (double)j / (double)TLEN;
    double sv, cv;
    sincos(ang, &sv, &cv);
    Wg[j] = make_double2(cv, sv);
}

// One block (256 thr = 4 waves) per sequence.
//  - no sincos/sqrt in the hot path (twiddles from ws; top-k on amp^2)
//  - padded LDS indices kill early-stage b128 bank conflicts
//  - FFT stages 1..7 intra-wave (no block barrier); 6 __syncthreads total
//  - nontemporal float4 output stores
__global__ __launch_bounds__(256) void periodicity_kernel(
    const float* __restrict__ x,
    const double2* __restrict__ Wg,
    float* __restrict__ out_g,
    float* __restrict__ out_m,
    float* __restrict__ out_a)
{
    const int s    = blockIdx.x;     // sequence id 0..4095
    const int tid  = threadIdx.x;    // 0..255
    const int lane = tid & 63;
    const int wave = tid >> 6;

    __shared__ float   seqf[TLEN];
    __shared__ double2 X[TLEN + (TLEN >> 4)];        // padded (544)
    __shared__ double2 W[256 + 16];                  // padded (272)
    __shared__ double  amp2[280];                    // PAD(256)=272 used
    __shared__ double  bestv[KP];
    __shared__ int     besti[KP];
    __shared__ int     Ps[KP], Cs[KP], Bs[KP];

    // ---- Phase 1: load column x[b, :, n] + twiddle table from ws ----
    const int b = s >> 7;            // / NCH
    const int n = s & (NCH - 1);
    const float* col = x + (size_t)b * TLEN * NCH + n;
    for (int i = tid; i < TLEN; i += 256)
        seqf[i] = col[(size_t)i * NCH];
    {
        double2 w = Wg[tid];         // L2-hot broadcast load
        W[PAD(tid)] = w;
    }
    __syncthreads();   // B1: seqf + W ready

    // ---- Phase 2: wave-local bit-reverse scatter into own 128-pt chunk ----
    {
        const int base = wave << 7;                  // 128*wave
        int i0 = base + lane, i1 = base + 64 + lane;
        int r0 = (int)(__brev((unsigned)i0) >> 23);  // 9-bit reverse
        int r1 = (int)(__brev((unsigned)i1) >> 23);
        X[PAD(i0)] = make_double2((double)seqf[r0], 0.0);
        X[PAD(i1)] = make_double2((double)seqf[r1], 0.0);
    }
    __builtin_amdgcn_wave_barrier();

    // stages 1..7: butterflies stay inside the wave's 128-pt chunk
    #pragma unroll
    for (int st = 1; st <= 7; ++st) {
        const int half = 1 << (st - 1);
        const int pos  = tid & (half - 1);
        const int i1   = ((tid >> (st - 1)) << st) + pos;
        const int i2   = i1 + half;
        const double2 wv = W[PAD(pos << (9 - st))];
        const double2 a  = X[PAD(i1)];
        const double2 c  = X[PAD(i2)];
        const double tr = wv.x * c.x - wv.y * c.y;
        const double ti = wv.x * c.y + wv.y * c.x;
        X[PAD(i1)] = make_double2(a.x + tr, a.y + ti);
        X[PAD(i2)] = make_double2(a.x - tr, a.y - ti);
        __builtin_amdgcn_wave_barrier();
    }

    // stages 8,9 cross waves
    #pragma unroll
    for (int st = 8; st <= 9; ++st) {
        __syncthreads();             // B2, B3
        const int half = 1 << (st - 1);
        const int pos  = tid & (half - 1);
        const int i1   = ((tid >> (st - 1)) << st) + pos;
        const int i2   = i1 + half;
        const double2 wv = W[PAD(pos << (9 - st))];
        const double2 a  = X[PAD(i1)];
        const double2 c  = X[PAD(i2)];
        const double tr = wv.x * c.x - wv.y * c.y;
        const double ti = wv.x * c.y + wv.y * c.x;
        X[PAD(i1)] = make_double2(a.x + tr, a.y + ti);
        X[PAD(i2)] = make_double2(a.x - tr, a.y - ti);
    }
    __syncthreads();                 // B4: X final

    // ---- Phase 3: squared amplitudes (ordering-equivalent), DC zeroed ----
    {
        double2 v = X[PAD(tid)];
        amp2[PAD(tid)] = (tid == 0) ? 0.0 : (v.x * v.x + v.y * v.y);
        if (tid == 0) {
            double2 vn = X[PAD(TLEN / 2)];
            amp2[PAD(TLEN / 2)] = vn.x * vn.x + vn.y * vn.y;
        }
    }
    __syncthreads();                 // B5: amp2 ready

    // ---- Phase 4: top-4 by wave 0 only (shfl butterflies, no barriers) ----
    if (wave == 0) {
        for (int q = 0; q < KP; ++q) {
            // scan increasing index with strict > : keeps SMALLEST index on
            // exact ties (jax top_k semantics)
            double v  = amp2[PAD(lane)];
            int    vi = lane;
            #pragma unroll
            for (int j = 1; j < 4; ++j) {
                double u = amp2[PAD(lane + 64 * j)];
                if (u > v) { v = u; vi = lane + 64 * j; }
            }
            if (lane == 0) {
                double u = amp2[PAD(256)];
                if (u > v) { v = u; vi = 256; }
            }
            // 64-lane butterfly argmax, smallest-index tie-break
            #pragma unroll
            for (int off = 32; off > 0; off >>= 1) {
                double ov = __shfl_xor(v, off, 64);
                int    oi = __shfl_xor(vi, off, 64);
                if (ov > v || (ov == v && oi < vi)) { v = ov; vi = oi; }
            }
            if (lane == 0) {
                bestv[q] = v;
                besti[q] = vi;
                amp2[PAD(vi)] = -1.0;   // exclude (amp2 >= 0)
            }
            __builtin_amdgcn_wave_barrier();
        }
        // periods / cycles / base + kamp out (lanes 0..3)
        if (lane < KP) {
            int ki = besti[lane];
            if (ki < 1) ki = 1;
            int P = TLEN / ki;
            P = P < MINP ? MINP : (P > PMAXV ? PMAXV : P);
            int cyc = TLEN / P;      // 8..32
            Ps[lane] = P;
            Cs[lane] = cyc;
            Bs[lane] = TLEN - cyc * P;
            // sqrt only for the 4 winners: identical bits to sqrt-then-select
            out_a[(size_t)s * KP + lane] = (float)sqrt(bestv[lane]);
        }
    }
    __syncthreads();                 // B6: params ready

    // ---- Phase 5: gather + mask, nontemporal float4 coalesced stores ----
    float* og = out_g + (size_t)s * (KP * CMAXV * PMAXV);
    float* om = out_m + (size_t)s * (KP * CMAXV * PMAXV);
    const int pp = (tid & 15) << 2;      // p offset 0..60 step 4
    for (int r = tid >> 4; r < KP * CMAXV; r += 16) {
        const int k = r >> 5;            // / CMAXV
        const int c = r & (CMAXV - 1);
        const int P = Ps[k], cyc = Cs[k], base = Bs[k];
        nfloat4 g = (nfloat4)(0.f, 0.f, 0.f, 0.f);
        nfloat4 m = (nfloat4)(0.f, 0.f, 0.f, 0.f);
        if (c < cyc) {
            const int idx = base + c * P + pp;   // in-bounds whenever p < P
            if (pp     < P) { g.x = seqf[idx];     m.x = 1.f; }
            if (pp + 1 < P) { g.y = seqf[idx + 1]; m.y = 1.f; }
            if (pp + 2 < P) { g.z = seqf[idx + 2]; m.z = 1.f; }
            if (pp + 3 < P) { g.w = seqf[idx + 3]; m.w = 1.f; }
        }
        __builtin_nontemporal_store(g, (nfloat4*)(og + r * PMAXV + pp));
        __builtin_nontemporal_store(m, (nfloat4*)(om + r * PMAXV + pp));
    }
}

extern "C" void kernel_launch(void* const* d_in, const int* in_sizes, int n_in,
                              void* d_out, int out_size, void* d_ws, size_t ws_size,
                              hipStream_t stream) {
    const float* x = (const float*)d_in[0];
    float* out = (float*)d_out;
    float* og = out;              // gathered: [B,N,K,Cmax,Pmax]
    float* om = out + OUTG;       // mask:     same shape
    float* oa = om + OUTG;        // kamp:     [B,N,K]
    double2* Wg = (double2*)d_ws; // 4 KB twiddle table

    twiddle_setup<<<dim3(1), dim3(256), 0, stream>>>(Wg);
    periodicity_kernel<<<dim3(NSEQ), dim3(256), 0, stream>>>(x, Wg, og, om, oa);
}